// Round 5
// baseline (388.023 us; speedup 1.0000x reference)
//
#include <hip/hip_runtime.h>

// Two-layer cached GCN. Round 11 (= round 10 resubmit, infra failure; one
// tweak: plain col loads instead of nontemporal — col is re-read 16x across
// XCD slices and must stay L3-served).
// XCD-sliced aggregation: ts stored column-slice-blocked ts_b[8][N][16]
// (gemm epilogue's nt-tile == 16-col slice, write is free). Agg grid uses
// slice = blockIdx.x & 7; default dispatch round-robins blocks across the
// 8 XCDs, so each XCD's L2 holds ONE 3.2MB slice and the random per-edge
// gathers become L2 hits instead of 8x-replicated HBM misses.

#define BKT_SHIFT 7
#define BKT_NODES 128
#define CH 8192
#define MAXBKT 1024

typedef _Float16 half4v __attribute__((ext_vector_type(4)));
typedef _Float16 half8v __attribute__((ext_vector_type(8)));
typedef float float4v __attribute__((ext_vector_type(4)));

// ---------------- prep: W1/W2 -> fp16 transposed, zero bcnt + done-counter ----
__global__ __launch_bounds__(256) void k_prep(const float* __restrict__ W1,
                                              const float* __restrict__ W2,
                                              _Float16* __restrict__ wt1,
                                              _Float16* __restrict__ wt2,
                                              int* __restrict__ bcnt,
                                              int* __restrict__ dcnt, int nbkt) {
    int i = blockIdx.x * 256 + threadIdx.x;   // 0..32767
    if (i < 16384) {
        int k = i >> 7, c = i & 127;
        wt1[c * 128 + k] = (_Float16)W1[i];
    } else {
        int j = i - 16384;
        int k = j >> 7, c = j & 127;
        wt2[c * 128 + k] = (_Float16)W2[j];
    }
    if (i < nbkt) bcnt[i] = 0;
    if (i < 2) dcnt[i] = 0;
}

// ---------------- bucket histogram + last-block exclusive scan ----------------
__global__ __launch_bounds__(256) void k_bincount_scan(const int* __restrict__ dst,
                                                       int* __restrict__ bcnt,
                                                       int* __restrict__ bofs,
                                                       int* __restrict__ bcur,
                                                       int* __restrict__ dcnt,
                                                       int E, int nbkt, int nblocks) {
    __shared__ int sh[MAXBKT];
    const int t = threadIdx.x;
    for (int i = t; i < nbkt; i += 256) sh[i] = 0;
    __syncthreads();
    for (long long e = (long long)blockIdx.x * 256 + t; e < E;
         e += (long long)nblocks * 256)
        atomicAdd(&sh[dst[e] >> BKT_SHIFT], 1);
    __syncthreads();
    for (int i = t; i < nbkt; i += 256)
        if (sh[i]) atomicAdd(&bcnt[i], sh[i]);   // device-scope, coherent
    __threadfence();
    __syncthreads();
    __shared__ int last;
    if (t == 0) last = (atomicAdd(&dcnt[0], 1) == nblocks - 1);
    __syncthreads();
    if (!last) return;
    __threadfence();
    // last block: exclusive scan of bcnt[0..nbkt), 4/thread, coherent reads.
    int v[4];
    int s = 0;
    for (int k = 0; k < 4; k++) {
        int idx = t * 4 + k;
        v[k] = (idx < nbkt) ? atomicAdd(&bcnt[idx], 0) : 0;
        s += v[k];
    }
    __syncthreads();
    int x = s;
    sh[t] = x;
    __syncthreads();
    for (int o = 1; o < 256; o <<= 1) {
        int y = (t >= o) ? sh[t - o] : 0;
        __syncthreads();
        x += y;
        sh[t] = x;
        __syncthreads();
    }
    int run = x - s;
    for (int k = 0; k < 4; k++) {
        int idx = t * 4 + k;
        if (idx < nbkt) { bofs[idx] = run; bcur[idx] = run; }
        run += v[k];
    }
    if (t == 0) bofs[nbkt] = E;
}

// ---------------- bulk-reservation bin fill (proven CH=8192 config) ----------
__global__ __launch_bounds__(256) void k_binfill(const int* __restrict__ src,
                                                 const int* __restrict__ dst,
                                                 int* __restrict__ bcur,
                                                 unsigned* __restrict__ recs,
                                                 int E, int nbkt) {
    __shared__ unsigned stage[CH];          // 32 KB
    __shared__ unsigned short stageb[CH];   // 16 KB
    __shared__ int cnt[MAXBKT];             // 4 KB
    __shared__ int base[MAXBKT];            // 4 KB
    const int t = threadIdx.x;
    const long long c0 = (long long)blockIdx.x * CH;

    for (int i = t; i < nbkt; i += 256) cnt[i] = 0;
    __syncthreads();

    for (int k = 0; k < CH / 256; k++) {
        int i = k * 256 + t;
        long long e = c0 + i;
        if (e < E) {
            int d = dst[e];
            int b = d >> BKT_SHIFT;
            stage[i] = ((unsigned)(d & (BKT_NODES - 1)) << 17) | (unsigned)src[e];
            stageb[i] = (unsigned short)b;
            atomicAdd(&cnt[b], 1);
        }
    }
    __syncthreads();

    for (int i = t; i < nbkt; i += 256) {
        int c = cnt[i];
        base[i] = c ? atomicAdd(&bcur[i], c) : 0;
        cnt[i] = 0;
    }
    __syncthreads();

    for (int k = 0; k < CH / 256; k++) {
        int i = k * 256 + t;
        if (c0 + i < E) {
            int b = stageb[i];
            int p = base[b] + atomicAdd(&cnt[b], 1);
            recs[p] = stage[i];
        }
    }
}

// ---------------- fused deg + scan + CSR fill ----------------
__global__ __launch_bounds__(256) void k_fill_all(const unsigned* __restrict__ recs,
                                                  const int* __restrict__ bofs,
                                                  float* __restrict__ dinv,
                                                  int* __restrict__ ofs,
                                                  int* __restrict__ col,
                                                  int n, int E) {
    __shared__ int cnt[BKT_NODES];
    __shared__ int sc[BKT_NODES];
    const int b = blockIdx.x, t = threadIdx.x;
    const int beg = bofs[b], end = bofs[b + 1];

    if (t < BKT_NODES) cnt[t] = 0;
    __syncthreads();
    for (int j = beg + t; j < end; j += 256)
        atomicAdd(&cnt[recs[j] >> 17], 1);
    __syncthreads();

    int v = 0, x = 0;
    if (t < BKT_NODES) { v = cnt[t]; x = v; sc[t] = x; }
    __syncthreads();
    for (int o = 1; o < BKT_NODES; o <<= 1) {
        int y = (t >= o && t < BKT_NODES) ? sc[t - o] : 0;
        __syncthreads();
        if (t < BKT_NODES) { x += y; sc[t] = x; }
        __syncthreads();
    }

    const int d0 = b << BKT_SHIFT;
    if (t < BKT_NODES) {
        int off = beg + x - v;
        int node = d0 + t;
        if (node < n) {
            ofs[node] = off;
            dinv[node] = rsqrtf((float)v + 1.0f);
        }
        cnt[t] = off;   // becomes cur
    }
    if (b == 0 && t == 0) ofs[n] = E;
    __syncthreads();

    for (int j = beg + t; j < end; j += 256) {
        unsigned r = recs[j];
        int p = atomicAdd(&cnt[r >> 17], 1);
        col[p] = (int)(r & 0x1FFFF);
    }
}

// ---------------- MFMA GEMM: ts_b[8][n][16](fp16) = dinv[row]*(in @ W) ------
// Column-slice-blocked output: slice s = nt tile (16 cols). A fragments
// straight from global; only W in LDS; 4 blocks/CU.
template <int IN_HALF>
__global__ __launch_bounds__(256, 4) void k_gemm_mfma(const void* __restrict__ inp,
                                                      const _Float16* __restrict__ Wt,
                                                      const float* __restrict__ dinv,
                                                      _Float16* __restrict__ tsb, int n) {
    __shared__ _Float16 Bl[128][136];  // 34.8 KB
    const int t = threadIdx.x;
    const int row0 = blockIdx.x * 64;

    for (int i = t; i < 128 * 16; i += 256) {
        int r = i >> 4, c8 = i & 15;
        *(half8v*)&Bl[r][c8 * 8] = *(const half8v*)&Wt[r * 128 + c8 * 8];
    }
    __syncthreads();

    const int wave = t >> 6;
    const int lane = t & 63;
    const int m0 = wave * 16;
    const int ml = lane & 15;
    const int quad = lane >> 4;

    int r = row0 + m0 + ml;
    if (r >= n) r = n - 1;   // clamp: OOB rows compute garbage, never stored

    float4v acc[8] = {};
#pragma unroll
    for (int kc = 0; kc < 4; kc++) {
        half8v a;
        if (IN_HALF) {
            a = *(const half8v*)((const _Float16*)inp + (size_t)r * 128 + kc * 32 + quad * 8);
        } else {
            const float* ap = (const float*)inp + (size_t)r * 128 + kc * 32 + quad * 8;
            float4v v0 = *(const float4v*)ap;
            float4v v1 = *(const float4v*)(ap + 4);
#pragma unroll
            for (int k = 0; k < 4; k++) {
                a[k] = (_Float16)v0[k];
                a[4 + k] = (_Float16)v1[k];
            }
        }
#pragma unroll
        for (int nt = 0; nt < 8; nt++) {
            half8v bfr = *(const half8v*)&Bl[nt * 16 + ml][kc * 32 + quad * 8];
            acc[nt] = __builtin_amdgcn_mfma_f32_16x16x32_f16(a, bfr, acc[nt], 0, 0, 0);
        }
    }

    int nr = n - row0;
    if (nr > 64) nr = 64;
#pragma unroll
    for (int reg = 0; reg < 4; reg++) {
        int rr = m0 + quad * 4 + reg;
        if (rr < nr) {
            float dv = dinv[row0 + rr];
#pragma unroll
            for (int nt = 0; nt < 8; nt++)
                tsb[(size_t)nt * n * 16 + (size_t)(row0 + rr) * 16 + ml] =
                    (_Float16)(acc[nt][reg] * dv);
        }
    }
}

// ---------------- XCD-sliced CSR aggregation ----------------
// slice = blockIdx.x & 7 -> (round-robin dispatch) all of slice s's blocks
// land on XCD s, whose L2 holds ts_b slice s (n*16 fp16 = 3.2 MB). Gathers
// become L2 hits. 2 threads/row, 8 cols (16B half8) each. Plain col loads
// (L3-served across the 8 XCD re-walks); nontemporal out stores only.
template <int OUT_HALF>
__global__ __launch_bounds__(256) void k_agg_slice(const int* __restrict__ ofs,
                                                   const int* __restrict__ col,
                                                   const float* __restrict__ dinv,
                                                   const _Float16* __restrict__ tsb,
                                                   const float* __restrict__ bias,
                                                   void* __restrict__ outp, int n) {
    const int blk = blockIdx.x;
    const int slice = blk & 7;
    const int chunk = blk >> 3;
    const int t = threadIdx.x;
    const int row = chunk * 128 + (t >> 1);
    if (row >= n) return;
    const int half = t & 1;
    const int c0 = slice * 16 + half * 8;
    const _Float16* base = tsb + (size_t)slice * n * 16 + half * 8;

    float dd = dinv[row];
    int beg = ofs[row];
    int end = ofs[row + 1];

    half8v sv = *(const half8v*)(base + (size_t)row * 16);
    float acc[8];
#pragma unroll
    for (int k = 0; k < 8; k++) acc[k] = (float)sv[k];

    int j = beg;
    for (; j + 3 < end; j += 4) {
        int s0 = col[j], s1 = col[j + 1], s2 = col[j + 2], s3 = col[j + 3];
        half8v v0 = *(const half8v*)(base + (size_t)s0 * 16);
        half8v v1 = *(const half8v*)(base + (size_t)s1 * 16);
        half8v v2 = *(const half8v*)(base + (size_t)s2 * 16);
        half8v v3 = *(const half8v*)(base + (size_t)s3 * 16);
#pragma unroll
        for (int k = 0; k < 8; k++)
            acc[k] += (float)v0[k] + (float)v1[k] + (float)v2[k] + (float)v3[k];
    }
    for (; j < end; j++) {
        int s = col[j];
        half8v v = *(const half8v*)(base + (size_t)s * 16);
#pragma unroll
        for (int k = 0; k < 8; k++) acc[k] += (float)v[k];
    }

    float4v bv0 = *(const float4v*)&bias[c0];
    float4v bv1 = *(const float4v*)&bias[c0 + 4];

    if (OUT_HALF) {
        half8v hv;
#pragma unroll
        for (int k = 0; k < 4; k++) {
            hv[k] = (_Float16)fmaxf(bv0[k] + dd * acc[k], 0.f);
            hv[4 + k] = (_Float16)fmaxf(bv1[k] + dd * acc[4 + k], 0.f);
        }
        __builtin_nontemporal_store(hv,
            (half8v*)((_Float16*)outp + (size_t)row * 128 + c0));
    } else {
        float4v o0, o1;
#pragma unroll
        for (int k = 0; k < 4; k++) {
            o0[k] = bv0[k] + dd * acc[k];
            o1[k] = bv1[k] + dd * acc[4 + k];
        }
        float* op = (float*)outp + (size_t)row * 128 + c0;
        __builtin_nontemporal_store(o0, (float4v*)op);
        __builtin_nontemporal_store(o1, (float4v*)(op + 4));
    }
}

extern "C" void kernel_launch(void* const* d_in, const int* in_sizes, int n_in,
                              void* d_out, int out_size, void* d_ws, size_t ws_size,
                              hipStream_t stream) {
    const int N = in_sizes[0] / 128;
    const int E = in_sizes[1] / 2;
    const float* x  = (const float*)d_in[0];
    const int*   ei = (const int*)d_in[1];
    const float* W1 = (const float*)d_in[2];
    const float* b1 = (const float*)d_in[3];
    const float* W2 = (const float*)d_in[4];
    const float* b2 = (const float*)d_in[5];

    const int* src = ei;
    const int* dst = ei + E;

    const int NBKT = (N + BKT_NODES - 1) / BKT_NODES;

    // ---- workspace layout ----
    _Float16* t    = (_Float16*)d_ws;            // N*128 (ts_b, slice-blocked)
    _Float16* wt1  = t + (size_t)N * 128;        // 16384
    _Float16* wt2  = wt1 + 16384;                // 16384
    float*    dinv = (float*)(wt2 + 16384);      // N
    int*      ofs  = (int*)(dinv + N);           // N+1
    unsigned* recs = (unsigned*)(ofs + ((N + 2 + 255) & ~255)); // E
    int*      col  = (int*)(recs + E);           // E
    int*      bofs = col + E;                    // NBKT+1
    int*      bcur = bofs + NBKT + 1;            // NBKT
    int*      bcnt = bcur + NBKT;                // NBKT
    int*      dcnt = bcnt + NBKT;                // 2 (done counters)

    // layer-1 hidden (fp16, relu applied) in front half of d_out;
    // final fp32 out overwrites d_out afterwards (h16 dead by then).
    _Float16* h16 = (_Float16*)d_out;
    float*    out = (float*)d_out;

    const int nb_g = (N + 63) / 64;
    const int nb_a = ((N + 127) / 128) * 8;
    const int nb_c = (int)(((long long)E + CH - 1) / CH);

    // ---- prep + binning + fused CSR build (4 dispatches) ----
    k_prep<<<128, 256, 0, stream>>>(W1, W2, wt1, wt2, bcnt, dcnt, NBKT);
    k_bincount_scan<<<256, 256, 0, stream>>>(dst, bcnt, bofs, bcur, dcnt, E, NBKT, 256);
    k_binfill<<<nb_c, 256, 0, stream>>>(src, dst, bcur, recs, E, NBKT);
    k_fill_all<<<NBKT, 256, 0, stream>>>(recs, bofs, dinv, ofs, col, N, E);

    // ---- layer 1: ts_b = dinv*(x@W1); h16 = relu(b1 + dinv*(agg ts_b)) ----
    k_gemm_mfma<0><<<nb_g, 256, 0, stream>>>(x, wt1, dinv, t, N);
    k_agg_slice<1><<<nb_a, 256, 0, stream>>>(ofs, col, dinv, t, b1, h16, N);

    // ---- layer 2: ts_b = dinv*(h16@W2); out = b2 + dinv*(agg ts_b) ----
    k_gemm_mfma<1><<<nb_g, 256, 0, stream>>>(h16, wt2, dinv, t, N);
    k_agg_slice<0><<<nb_a, 256, 0, stream>>>(ofs, col, dinv, t, b2, out, N);
}

// Round 6
// 336.899 us; speedup vs baseline: 1.1517x; 1.1517x over previous
//
#include <hip/hip_runtime.h>

// Two-layer cached GCN. Round 12:
// (a) agg reverted to round-9-proven form (32 lanes/row, half4v; agg<1>
//     writes fp16+relu h16). XCD-slicing (round 11) cut L2-fill 190->141MB
//     but cost +32us from 8x edge-list re-walks — reverted.
// (b) gemm epilogue: C-tile staged in LDS then half8 16-B coalesced stores
//     (was 32 scalar 2-B stores/lane — suspected hidden ~20us/gemm).
// (c) binfill: drop 48KB LDS staging, re-read src/dst from L2 in pass 2
//     (8KB LDS -> wave-bound occupancy instead of 2 blocks/CU).

#define BKT_SHIFT 7
#define BKT_NODES 128
#define CH 8192
#define MAXBKT 1024

typedef _Float16 half4v __attribute__((ext_vector_type(4)));
typedef _Float16 half8v __attribute__((ext_vector_type(8)));
typedef float float4v __attribute__((ext_vector_type(4)));

// ---------------- prep: W1/W2 -> fp16 transposed, zero bcnt + done-counter ----
__global__ __launch_bounds__(256) void k_prep(const float* __restrict__ W1,
                                              const float* __restrict__ W2,
                                              _Float16* __restrict__ wt1,
                                              _Float16* __restrict__ wt2,
                                              int* __restrict__ bcnt,
                                              int* __restrict__ dcnt, int nbkt) {
    int i = blockIdx.x * 256 + threadIdx.x;   // 0..32767
    if (i < 16384) {
        int k = i >> 7, c = i & 127;
        wt1[c * 128 + k] = (_Float16)W1[i];
    } else {
        int j = i - 16384;
        int k = j >> 7, c = j & 127;
        wt2[c * 128 + k] = (_Float16)W2[j];
    }
    if (i < nbkt) bcnt[i] = 0;
    if (i < 2) dcnt[i] = 0;
}

// ---------------- bucket histogram + last-block exclusive scan ----------------
__global__ __launch_bounds__(256) void k_bincount_scan(const int* __restrict__ dst,
                                                       int* __restrict__ bcnt,
                                                       int* __restrict__ bofs,
                                                       int* __restrict__ bcur,
                                                       int* __restrict__ dcnt,
                                                       int E, int nbkt, int nblocks) {
    __shared__ int sh[MAXBKT];
    const int t = threadIdx.x;
    for (int i = t; i < nbkt; i += 256) sh[i] = 0;
    __syncthreads();
    for (long long e = (long long)blockIdx.x * 256 + t; e < E;
         e += (long long)nblocks * 256)
        atomicAdd(&sh[dst[e] >> BKT_SHIFT], 1);
    __syncthreads();
    for (int i = t; i < nbkt; i += 256)
        if (sh[i]) atomicAdd(&bcnt[i], sh[i]);   // device-scope, coherent
    __threadfence();
    __syncthreads();
    __shared__ int last;
    if (t == 0) last = (atomicAdd(&dcnt[0], 1) == nblocks - 1);
    __syncthreads();
    if (!last) return;
    __threadfence();
    // last block: exclusive scan of bcnt[0..nbkt), 4/thread, coherent reads.
    int v[4];
    int s = 0;
    for (int k = 0; k < 4; k++) {
        int idx = t * 4 + k;
        v[k] = (idx < nbkt) ? atomicAdd(&bcnt[idx], 0) : 0;
        s += v[k];
    }
    __syncthreads();
    int x = s;
    sh[t] = x;
    __syncthreads();
    for (int o = 1; o < 256; o <<= 1) {
        int y = (t >= o) ? sh[t - o] : 0;
        __syncthreads();
        x += y;
        sh[t] = x;
        __syncthreads();
    }
    int run = x - s;
    for (int k = 0; k < 4; k++) {
        int idx = t * 4 + k;
        if (idx < nbkt) { bofs[idx] = run; bcur[idx] = run; }
        run += v[k];
    }
    if (t == 0) bofs[nbkt] = E;
}

// ---------------- bulk-reservation bin fill (re-read, 8KB LDS) ----------
__global__ __launch_bounds__(256) void k_binfill(const int* __restrict__ src,
                                                 const int* __restrict__ dst,
                                                 int* __restrict__ bcur,
                                                 unsigned* __restrict__ recs,
                                                 int E, int nbkt) {
    __shared__ int cnt[MAXBKT];   // 4 KB
    __shared__ int base[MAXBKT];  // 4 KB
    const int t = threadIdx.x;
    const long long c0 = (long long)blockIdx.x * CH;
    int lim = (int)(((long long)E - c0) < CH ? (E - c0) : CH);

    for (int i = t; i < nbkt; i += 256) cnt[i] = 0;
    __syncthreads();

    for (int i = t; i < lim; i += 256)
        atomicAdd(&cnt[dst[c0 + i] >> BKT_SHIFT], 1);
    __syncthreads();

    for (int i = t; i < nbkt; i += 256) {
        int c = cnt[i];
        base[i] = c ? atomicAdd(&bcur[i], c) : 0;
        cnt[i] = 0;
    }
    __syncthreads();

    // second pass: re-read src/dst (32 KB/block each, L1/L2-hot)
    for (int i = t; i < lim; i += 256) {
        int d = dst[c0 + i];
        int b = d >> BKT_SHIFT;
        int p = base[b] + atomicAdd(&cnt[b], 1);
        recs[p] = ((unsigned)(d & (BKT_NODES - 1)) << 17) | (unsigned)src[c0 + i];
    }
}

// ---------------- fused deg + scan + CSR fill ----------------
__global__ __launch_bounds__(256) void k_fill_all(const unsigned* __restrict__ recs,
                                                  const int* __restrict__ bofs,
                                                  float* __restrict__ dinv,
                                                  int* __restrict__ ofs,
                                                  int* __restrict__ col,
                                                  int n, int E) {
    __shared__ int cnt[BKT_NODES];
    __shared__ int sc[BKT_NODES];
    const int b = blockIdx.x, t = threadIdx.x;
    const int beg = bofs[b], end = bofs[b + 1];

    if (t < BKT_NODES) cnt[t] = 0;
    __syncthreads();
    for (int j = beg + t; j < end; j += 256)
        atomicAdd(&cnt[recs[j] >> 17], 1);
    __syncthreads();

    int v = 0, x = 0;
    if (t < BKT_NODES) { v = cnt[t]; x = v; sc[t] = x; }
    __syncthreads();
    for (int o = 1; o < BKT_NODES; o <<= 1) {
        int y = (t >= o && t < BKT_NODES) ? sc[t - o] : 0;
        __syncthreads();
        if (t < BKT_NODES) { x += y; sc[t] = x; }
        __syncthreads();
    }

    const int d0 = b << BKT_SHIFT;
    if (t < BKT_NODES) {
        int off = beg + x - v;
        int node = d0 + t;
        if (node < n) {
            ofs[node] = off;
            dinv[node] = rsqrtf((float)v + 1.0f);
        }
        cnt[t] = off;   // becomes cur
    }
    if (b == 0 && t == 0) ofs[n] = E;
    __syncthreads();

    for (int j = beg + t; j < end; j += 256) {
        unsigned r = recs[j];
        int p = atomicAdd(&cnt[r >> 17], 1);
        col[p] = (int)(r & 0x1FFFF);
    }
}

// ---------------- MFMA GEMM: ts[N x 128](fp16) = dinv[row] * (in @ W) ------
// A fragments straight from global (read-once); W in LDS; epilogue stages
// the C-tile in LDS so global stores are half8 (16B) fully coalesced
// instead of 32 scalar 2-B stores per lane. 52 KB LDS -> 3 blocks/CU.
template <int IN_HALF>
__global__ __launch_bounds__(256, 3) void k_gemm_mfma(const void* __restrict__ inp,
                                                      const _Float16* __restrict__ Wt,
                                                      const float* __restrict__ dinv,
                                                      _Float16* __restrict__ out, int n) {
    __shared__ _Float16 Bl[128][136];  // 34.8 KB
    __shared__ _Float16 Cl[64][136];   // 17.4 KB
    const int t = threadIdx.x;
    const int row0 = blockIdx.x * 64;

    for (int i = t; i < 128 * 16; i += 256) {
        int r = i >> 4, c8 = i & 15;
        *(half8v*)&Bl[r][c8 * 8] = *(const half8v*)&Wt[r * 128 + c8 * 8];
    }
    __syncthreads();

    const int wave = t >> 6;
    const int lane = t & 63;
    const int m0 = wave * 16;
    const int ml = lane & 15;
    const int quad = lane >> 4;

    int r = row0 + m0 + ml;
    if (r >= n) r = n - 1;   // clamp: OOB rows compute garbage, never stored

    float4v acc[8] = {};
#pragma unroll
    for (int kc = 0; kc < 4; kc++) {
        half8v a;
        if (IN_HALF) {
            a = *(const half8v*)((const _Float16*)inp + (size_t)r * 128 + kc * 32 + quad * 8);
        } else {
            const float* ap = (const float*)inp + (size_t)r * 128 + kc * 32 + quad * 8;
            float4v v0 = *(const float4v*)ap;
            float4v v1 = *(const float4v*)(ap + 4);
#pragma unroll
            for (int k = 0; k < 4; k++) {
                a[k] = (_Float16)v0[k];
                a[4 + k] = (_Float16)v1[k];
            }
        }
#pragma unroll
        for (int nt = 0; nt < 8; nt++) {
            half8v bfr = *(const half8v*)&Bl[nt * 16 + ml][kc * 32 + quad * 8];
            acc[nt] = __builtin_amdgcn_mfma_f32_16x16x32_f16(a, bfr, acc[nt], 0, 0, 0);
        }
    }

    int nr = n - row0;
    if (nr > 64) nr = 64;
    // stage D into Cl (scalar 2-B LDS writes, distinct addresses)
#pragma unroll
    for (int reg = 0; reg < 4; reg++) {
        int rr = m0 + quad * 4 + reg;
        float dv = (rr < nr) ? dinv[row0 + rr] : 0.f;
#pragma unroll
        for (int nt = 0; nt < 8; nt++)
            Cl[rr][nt * 16 + ml] = (_Float16)(acc[nt][reg] * dv);
    }
    __syncthreads();
    // coalesced half8 stores
    for (int i = t; i < 64 * 16; i += 256) {
        int rr = i >> 4, c8 = i & 15;
        if (rr < nr)
            *(half8v*)&out[(size_t)(row0 + rr) * 128 + c8 * 8] =
                *(const half8v*)&Cl[rr][c8 * 8];
    }
}

// ---------------- CSR aggregation (round-9-proven 32-lane form) ----------------
template <int OUT_HALF>
__global__ __launch_bounds__(256) void k_agg_csr(const int* __restrict__ ofs,
                                                 const int* __restrict__ col,
                                                 const float* __restrict__ dinv,
                                                 const half4v* __restrict__ ts,
                                                 const float* __restrict__ bias,
                                                 void* __restrict__ outp, int n) {
    int gid = blockIdx.x * 256 + threadIdx.x;
    int row = gid >> 5;
    int lane = gid & 31;
    if (row >= n) return;

    float dd = dinv[row];
    int beg = ofs[row];
    int end = ofs[row + 1];

    half4v sv = ts[(size_t)row * 32 + lane];
    float4 acc = make_float4((float)sv[0], (float)sv[1], (float)sv[2], (float)sv[3]);

    int j = beg;
    for (; j + 3 < end; j += 4) {
        int s0 = col[j], s1 = col[j + 1], s2 = col[j + 2], s3 = col[j + 3];
        half4v v0 = ts[(size_t)s0 * 32 + lane];
        half4v v1 = ts[(size_t)s1 * 32 + lane];
        half4v v2 = ts[(size_t)s2 * 32 + lane];
        half4v v3 = ts[(size_t)s3 * 32 + lane];
        acc.x += (float)v0[0] + (float)v1[0] + (float)v2[0] + (float)v3[0];
        acc.y += (float)v0[1] + (float)v1[1] + (float)v2[1] + (float)v3[1];
        acc.z += (float)v0[2] + (float)v1[2] + (float)v2[2] + (float)v3[2];
        acc.w += (float)v0[3] + (float)v1[3] + (float)v2[3] + (float)v3[3];
    }
    for (; j < end; j++) {
        half4v v = ts[(size_t)col[j] * 32 + lane];
        acc.x += (float)v[0];
        acc.y += (float)v[1];
        acc.z += (float)v[2];
        acc.w += (float)v[3];
    }

    float4 bv = *(const float4*)&bias[lane * 4];
    if (OUT_HALF) {
        half4v hv;
        hv[0] = (_Float16)fmaxf(bv.x + dd * acc.x, 0.f);
        hv[1] = (_Float16)fmaxf(bv.y + dd * acc.y, 0.f);
        hv[2] = (_Float16)fmaxf(bv.z + dd * acc.z, 0.f);
        hv[3] = (_Float16)fmaxf(bv.w + dd * acc.w, 0.f);
        ((half4v*)outp)[(size_t)row * 32 + lane] = hv;
    } else {
        float4 o;
        o.x = bv.x + dd * acc.x;
        o.y = bv.y + dd * acc.y;
        o.z = bv.z + dd * acc.z;
        o.w = bv.w + dd * acc.w;
        *(float4*)&((float*)outp)[(size_t)row * 128 + lane * 4] = o;
    }
}

extern "C" void kernel_launch(void* const* d_in, const int* in_sizes, int n_in,
                              void* d_out, int out_size, void* d_ws, size_t ws_size,
                              hipStream_t stream) {
    const int N = in_sizes[0] / 128;
    const int E = in_sizes[1] / 2;
    const float* x  = (const float*)d_in[0];
    const int*   ei = (const int*)d_in[1];
    const float* W1 = (const float*)d_in[2];
    const float* b1 = (const float*)d_in[3];
    const float* W2 = (const float*)d_in[4];
    const float* b2 = (const float*)d_in[5];

    const int* src = ei;
    const int* dst = ei + E;

    const int NBKT = (N + BKT_NODES - 1) / BKT_NODES;

    // ---- workspace layout ----
    _Float16* t    = (_Float16*)d_ws;            // N*128 (ts, reused per layer)
    _Float16* wt1  = t + (size_t)N * 128;        // 16384
    _Float16* wt2  = wt1 + 16384;                // 16384
    float*    dinv = (float*)(wt2 + 16384);      // N
    int*      ofs  = (int*)(dinv + N);           // N+1
    unsigned* recs = (unsigned*)(ofs + ((N + 2 + 255) & ~255)); // E
    int*      col  = (int*)(recs + E);           // E
    int*      bofs = col + E;                    // NBKT+1
    int*      bcur = bofs + NBKT + 1;            // NBKT
    int*      bcnt = bcur + NBKT;                // NBKT
    int*      dcnt = bcnt + NBKT;                // 2 (done counters)

    // layer-1 hidden (fp16, relu applied) in front half of d_out;
    // final fp32 out overwrites d_out afterwards (h16 dead by then).
    _Float16* h16 = (_Float16*)d_out;
    float*    out = (float*)d_out;

    const int nb_g = (N + 63) / 64;
    const int nb_a = (int)(((long long)N * 32 + 255) / 256);
    const int nb_c = (int)(((long long)E + CH - 1) / CH);

    // ---- prep + binning + fused CSR build (4 dispatches) ----
    k_prep<<<128, 256, 0, stream>>>(W1, W2, wt1, wt2, bcnt, dcnt, NBKT);
    k_bincount_scan<<<256, 256, 0, stream>>>(dst, bcnt, bofs, bcur, dcnt, E, NBKT, 256);
    k_binfill<<<nb_c, 256, 0, stream>>>(src, dst, bcur, recs, E, NBKT);
    k_fill_all<<<NBKT, 256, 0, stream>>>(recs, bofs, dinv, ofs, col, N, E);

    // ---- layer 1: ts = dinv*(x@W1); h16 = relu(b1 + dinv*(ts[d] + sum ts[col])) ----
    k_gemm_mfma<0><<<nb_g, 256, 0, stream>>>(x, wt1, dinv, t, N);
    k_agg_csr<1><<<nb_a, 256, 0, stream>>>(ofs, col, dinv, (const half4v*)t, b1, h16, N);

    // ---- layer 2: ts = dinv*(h16@W2); out = b2 + dinv*(ts[d] + sum ts[col]) ----
    k_gemm_mfma<1><<<nb_g, 256, 0, stream>>>(h16, wt2, dinv, t, N);
    k_agg_csr<0><<<nb_a, 256, 0, stream>>>(ofs, col, dinv, (const half4v*)t, b2, out, N);
}

// Round 7
// 321.314 us; speedup vs baseline: 1.2076x; 1.0485x over previous
//
#include <hip/hip_runtime.h>

// Two-layer cached GCN. Round 13 = exact round-9 kernel (proven 328.1us;
// round-12's gemm-epilogue-staging + binfill-re-read both reverted, they
// cost +9us) + ONE change: agg gather unroll x4 -> x8.
// Rationale: ts is L3-resident (25.6MB < 256MB), so FETCH_SIZE=190MB is
// L2-fill traffic mostly served by L3; VALUBusy=29%/occ=70% suggests the
// gather is LATENCY-bound (4 concurrent ~500cy gathers/wave), not at a BW
// ceiling. x8 unroll doubles memory-level parallelism per wave. Two
// accumulator chains shorten the FP-add dependency. If dur is unchanged,
// 3.7TB/s is the fabric ceiling and agg is closed.

#define BKT_SHIFT 7
#define BKT_NODES 128
#define CH 8192
#define MAXBKT 1024

typedef _Float16 half4v __attribute__((ext_vector_type(4)));
typedef _Float16 half8v __attribute__((ext_vector_type(8)));
typedef float float4v __attribute__((ext_vector_type(4)));

// ---------------- prep: W1/W2 -> fp16 transposed, zero bcnt + done-counter ----
__global__ __launch_bounds__(256) void k_prep(const float* __restrict__ W1,
                                              const float* __restrict__ W2,
                                              _Float16* __restrict__ wt1,
                                              _Float16* __restrict__ wt2,
                                              int* __restrict__ bcnt,
                                              int* __restrict__ dcnt, int nbkt) {
    int i = blockIdx.x * 256 + threadIdx.x;   // 0..32767
    if (i < 16384) {
        int k = i >> 7, c = i & 127;
        wt1[c * 128 + k] = (_Float16)W1[i];
    } else {
        int j = i - 16384;
        int k = j >> 7, c = j & 127;
        wt2[c * 128 + k] = (_Float16)W2[j];
    }
    if (i < nbkt) bcnt[i] = 0;
    if (i < 2) dcnt[i] = 0;
}

// ---------------- bucket histogram + last-block exclusive scan ----------------
__global__ __launch_bounds__(256) void k_bincount_scan(const int* __restrict__ dst,
                                                       int* __restrict__ bcnt,
                                                       int* __restrict__ bofs,
                                                       int* __restrict__ bcur,
                                                       int* __restrict__ dcnt,
                                                       int E, int nbkt, int nblocks) {
    __shared__ int sh[MAXBKT];
    const int t = threadIdx.x;
    for (int i = t; i < nbkt; i += 256) sh[i] = 0;
    __syncthreads();
    for (long long e = (long long)blockIdx.x * 256 + t; e < E;
         e += (long long)nblocks * 256)
        atomicAdd(&sh[dst[e] >> BKT_SHIFT], 1);
    __syncthreads();
    for (int i = t; i < nbkt; i += 256)
        if (sh[i]) atomicAdd(&bcnt[i], sh[i]);   // device-scope, coherent
    __threadfence();
    __syncthreads();
    __shared__ int last;
    if (t == 0) last = (atomicAdd(&dcnt[0], 1) == nblocks - 1);
    __syncthreads();
    if (!last) return;
    __threadfence();
    // last block: exclusive scan of bcnt[0..nbkt), 4/thread, coherent reads.
    int v[4];
    int s = 0;
    for (int k = 0; k < 4; k++) {
        int idx = t * 4 + k;
        v[k] = (idx < nbkt) ? atomicAdd(&bcnt[idx], 0) : 0;
        s += v[k];
    }
    __syncthreads();
    int x = s;
    sh[t] = x;
    __syncthreads();
    for (int o = 1; o < 256; o <<= 1) {
        int y = (t >= o) ? sh[t - o] : 0;
        __syncthreads();
        x += y;
        sh[t] = x;
        __syncthreads();
    }
    int run = x - s;
    for (int k = 0; k < 4; k++) {
        int idx = t * 4 + k;
        if (idx < nbkt) { bofs[idx] = run; bcur[idx] = run; }
        run += v[k];
    }
    if (t == 0) bofs[nbkt] = E;
}

// ---------------- bulk-reservation bin fill (proven CH=8192 config) ----------
__global__ __launch_bounds__(256) void k_binfill(const int* __restrict__ src,
                                                 const int* __restrict__ dst,
                                                 int* __restrict__ bcur,
                                                 unsigned* __restrict__ recs,
                                                 int E, int nbkt) {
    __shared__ unsigned stage[CH];          // 32 KB
    __shared__ unsigned short stageb[CH];   // 16 KB
    __shared__ int cnt[MAXBKT];             // 4 KB
    __shared__ int base[MAXBKT];            // 4 KB
    const int t = threadIdx.x;
    const long long c0 = (long long)blockIdx.x * CH;

    for (int i = t; i < nbkt; i += 256) cnt[i] = 0;
    __syncthreads();

    for (int k = 0; k < CH / 256; k++) {
        int i = k * 256 + t;
        long long e = c0 + i;
        if (e < E) {
            int d = dst[e];
            int b = d >> BKT_SHIFT;
            stage[i] = ((unsigned)(d & (BKT_NODES - 1)) << 17) | (unsigned)src[e];
            stageb[i] = (unsigned short)b;
            atomicAdd(&cnt[b], 1);
        }
    }
    __syncthreads();

    for (int i = t; i < nbkt; i += 256) {
        int c = cnt[i];
        base[i] = c ? atomicAdd(&bcur[i], c) : 0;
        cnt[i] = 0;
    }
    __syncthreads();

    for (int k = 0; k < CH / 256; k++) {
        int i = k * 256 + t;
        if (c0 + i < E) {
            int b = stageb[i];
            int p = base[b] + atomicAdd(&cnt[b], 1);
            recs[p] = stage[i];
        }
    }
}

// ---------------- fused deg + scan + CSR fill ----------------
__global__ __launch_bounds__(256) void k_fill_all(const unsigned* __restrict__ recs,
                                                  const int* __restrict__ bofs,
                                                  float* __restrict__ dinv,
                                                  int* __restrict__ ofs,
                                                  int* __restrict__ col,
                                                  int n, int E) {
    __shared__ int cnt[BKT_NODES];
    __shared__ int sc[BKT_NODES];
    const int b = blockIdx.x, t = threadIdx.x;
    const int beg = bofs[b], end = bofs[b + 1];

    if (t < BKT_NODES) cnt[t] = 0;
    __syncthreads();
    for (int j = beg + t; j < end; j += 256)
        atomicAdd(&cnt[recs[j] >> 17], 1);
    __syncthreads();

    int v = 0, x = 0;
    if (t < BKT_NODES) { v = cnt[t]; x = v; sc[t] = x; }
    __syncthreads();
    for (int o = 1; o < BKT_NODES; o <<= 1) {
        int y = (t >= o && t < BKT_NODES) ? sc[t - o] : 0;
        __syncthreads();
        if (t < BKT_NODES) { x += y; sc[t] = x; }
        __syncthreads();
    }

    const int d0 = b << BKT_SHIFT;
    if (t < BKT_NODES) {
        int off = beg + x - v;
        int node = d0 + t;
        if (node < n) {
            ofs[node] = off;
            dinv[node] = rsqrtf((float)v + 1.0f);
        }
        cnt[t] = off;   // becomes cur
    }
    if (b == 0 && t == 0) ofs[n] = E;
    __syncthreads();

    for (int j = beg + t; j < end; j += 256) {
        unsigned r = recs[j];
        int p = atomicAdd(&cnt[r >> 17], 1);
        col[p] = (int)(r & 0x1FFFF);
    }
}

// ---------------- MFMA GEMM: ts[N x 128](fp16) = dinv[row] * (in @ W) ------
// A fragments straight from global (read-once); only W in LDS; 4 blocks/CU.
template <int IN_HALF>
__global__ __launch_bounds__(256, 4) void k_gemm_mfma(const void* __restrict__ inp,
                                                      const _Float16* __restrict__ Wt,
                                                      const float* __restrict__ dinv,
                                                      _Float16* __restrict__ out, int n) {
    __shared__ _Float16 Bl[128][136];  // 34.8 KB
    const int t = threadIdx.x;
    const int row0 = blockIdx.x * 64;

    for (int i = t; i < 128 * 16; i += 256) {
        int r = i >> 4, c8 = i & 15;
        *(half8v*)&Bl[r][c8 * 8] = *(const half8v*)&Wt[r * 128 + c8 * 8];
    }
    __syncthreads();

    const int wave = t >> 6;
    const int lane = t & 63;
    const int m0 = wave * 16;
    const int ml = lane & 15;
    const int quad = lane >> 4;

    int r = row0 + m0 + ml;
    if (r >= n) r = n - 1;   // clamp: OOB rows compute garbage, never stored

    float4v acc[8] = {};
#pragma unroll
    for (int kc = 0; kc < 4; kc++) {
        half8v a;
        if (IN_HALF) {
            a = *(const half8v*)((const _Float16*)inp + (size_t)r * 128 + kc * 32 + quad * 8);
        } else {
            const float* ap = (const float*)inp + (size_t)r * 128 + kc * 32 + quad * 8;
            float4v v0 = *(const float4v*)ap;
            float4v v1 = *(const float4v*)(ap + 4);
#pragma unroll
            for (int k = 0; k < 4; k++) {
                a[k] = (_Float16)v0[k];
                a[4 + k] = (_Float16)v1[k];
            }
        }
#pragma unroll
        for (int nt = 0; nt < 8; nt++) {
            half8v bfr = *(const half8v*)&Bl[nt * 16 + ml][kc * 32 + quad * 8];
            acc[nt] = __builtin_amdgcn_mfma_f32_16x16x32_f16(a, bfr, acc[nt], 0, 0, 0);
        }
    }

    int nr = n - row0;
    if (nr > 64) nr = 64;
#pragma unroll
    for (int reg = 0; reg < 4; reg++) {
        int rr = m0 + quad * 4 + reg;
        if (rr < nr) {
            float dv = dinv[row0 + rr];
#pragma unroll
            for (int nt = 0; nt < 8; nt++)
                out[(size_t)(row0 + rr) * 128 + nt * 16 + ml] =
                    (_Float16)(acc[nt][reg] * dv);
        }
    }
}

// ---------------- CSR aggregation (32-lane form, gather unroll x8) ----------
// OUT_HALF=1: out = relu(b + dinv*acc) as fp16 (layer-1 hidden; exact since
// gemm-2 re-quantizes to fp16 anyway and relu commutes with rounding).
template <int OUT_HALF>
__global__ __launch_bounds__(256) void k_agg_csr(const int* __restrict__ ofs,
                                                 const int* __restrict__ col,
                                                 const float* __restrict__ dinv,
                                                 const half4v* __restrict__ ts,
                                                 const float* __restrict__ bias,
                                                 void* __restrict__ outp, int n) {
    int gid = blockIdx.x * 256 + threadIdx.x;
    int row = gid >> 5;
    int lane = gid & 31;
    if (row >= n) return;

    float dd = dinv[row];
    int beg = ofs[row];
    int end = ofs[row + 1];

    half4v sv = ts[(size_t)row * 32 + lane];
    float4 acc = make_float4((float)sv[0], (float)sv[1], (float)sv[2], (float)sv[3]);
    float4 acc2 = make_float4(0.f, 0.f, 0.f, 0.f);

    int j = beg;
    for (; j + 7 < end; j += 8) {
        int s0 = col[j],     s1 = col[j + 1], s2 = col[j + 2], s3 = col[j + 3];
        int s4 = col[j + 4], s5 = col[j + 5], s6 = col[j + 6], s7 = col[j + 7];
        half4v v0 = ts[(size_t)s0 * 32 + lane];
        half4v v1 = ts[(size_t)s1 * 32 + lane];
        half4v v2 = ts[(size_t)s2 * 32 + lane];
        half4v v3 = ts[(size_t)s3 * 32 + lane];
        half4v v4 = ts[(size_t)s4 * 32 + lane];
        half4v v5 = ts[(size_t)s5 * 32 + lane];
        half4v v6 = ts[(size_t)s6 * 32 + lane];
        half4v v7 = ts[(size_t)s7 * 32 + lane];
        acc.x  += (float)v0[0] + (float)v1[0] + (float)v2[0] + (float)v3[0];
        acc.y  += (float)v0[1] + (float)v1[1] + (float)v2[1] + (float)v3[1];
        acc.z  += (float)v0[2] + (float)v1[2] + (float)v2[2] + (float)v3[2];
        acc.w  += (float)v0[3] + (float)v1[3] + (float)v2[3] + (float)v3[3];
        acc2.x += (float)v4[0] + (float)v5[0] + (float)v6[0] + (float)v7[0];
        acc2.y += (float)v4[1] + (float)v5[1] + (float)v6[1] + (float)v7[1];
        acc2.z += (float)v4[2] + (float)v5[2] + (float)v6[2] + (float)v7[2];
        acc2.w += (float)v4[3] + (float)v5[3] + (float)v6[3] + (float)v7[3];
    }
    for (; j + 3 < end; j += 4) {
        int s0 = col[j], s1 = col[j + 1], s2 = col[j + 2], s3 = col[j + 3];
        half4v v0 = ts[(size_t)s0 * 32 + lane];
        half4v v1 = ts[(size_t)s1 * 32 + lane];
        half4v v2 = ts[(size_t)s2 * 32 + lane];
        half4v v3 = ts[(size_t)s3 * 32 + lane];
        acc.x += (float)v0[0] + (float)v1[0] + (float)v2[0] + (float)v3[0];
        acc.y += (float)v0[1] + (float)v1[1] + (float)v2[1] + (float)v3[1];
        acc.z += (float)v0[2] + (float)v1[2] + (float)v2[2] + (float)v3[2];
        acc.w += (float)v0[3] + (float)v1[3] + (float)v2[3] + (float)v3[3];
    }
    for (; j < end; j++) {
        half4v v = ts[(size_t)col[j] * 32 + lane];
        acc.x += (float)v[0];
        acc.y += (float)v[1];
        acc.z += (float)v[2];
        acc.w += (float)v[3];
    }
    acc.x += acc2.x; acc.y += acc2.y; acc.z += acc2.z; acc.w += acc2.w;

    float4 bv = *(const float4*)&bias[lane * 4];
    if (OUT_HALF) {
        half4v hv;
        hv[0] = (_Float16)fmaxf(bv.x + dd * acc.x, 0.f);
        hv[1] = (_Float16)fmaxf(bv.y + dd * acc.y, 0.f);
        hv[2] = (_Float16)fmaxf(bv.z + dd * acc.z, 0.f);
        hv[3] = (_Float16)fmaxf(bv.w + dd * acc.w, 0.f);
        ((half4v*)outp)[(size_t)row * 32 + lane] = hv;
    } else {
        float4 o;
        o.x = bv.x + dd * acc.x;
        o.y = bv.y + dd * acc.y;
        o.z = bv.z + dd * acc.z;
        o.w = bv.w + dd * acc.w;
        *(float4*)&((float*)outp)[(size_t)row * 128 + lane * 4] = o;
    }
}

extern "C" void kernel_launch(void* const* d_in, const int* in_sizes, int n_in,
                              void* d_out, int out_size, void* d_ws, size_t ws_size,
                              hipStream_t stream) {
    const int N = in_sizes[0] / 128;
    const int E = in_sizes[1] / 2;
    const float* x  = (const float*)d_in[0];
    const int*   ei = (const int*)d_in[1];
    const float* W1 = (const float*)d_in[2];
    const float* b1 = (const float*)d_in[3];
    const float* W2 = (const float*)d_in[4];
    const float* b2 = (const float*)d_in[5];

    const int* src = ei;
    const int* dst = ei + E;

    const int NBKT = (N + BKT_NODES - 1) / BKT_NODES;

    // ---- workspace layout ----
    _Float16* t    = (_Float16*)d_ws;            // N*128 (ts, reused per layer)
    _Float16* wt1  = t + (size_t)N * 128;        // 16384
    _Float16* wt2  = wt1 + 16384;                // 16384
    float*    dinv = (float*)(wt2 + 16384);      // N
    int*      ofs  = (int*)(dinv + N);           // N+1
    unsigned* recs = (unsigned*)(ofs + ((N + 2 + 255) & ~255)); // E
    int*      col  = (int*)(recs + E);           // E
    int*      bofs = col + E;                    // NBKT+1
    int*      bcur = bofs + NBKT + 1;            // NBKT
    int*      bcnt = bcur + NBKT;                // NBKT
    int*      dcnt = bcnt + NBKT;                // 2 (done counters)

    // layer-1 hidden (fp16, relu applied) in front half of d_out;
    // final fp32 out overwrites d_out afterwards (h16 dead by then).
    _Float16* h16 = (_Float16*)d_out;
    float*    out = (float*)d_out;

    const int nb_g = (N + 63) / 64;
    const int nb_a = (int)(((long long)N * 32 + 255) / 256);
    const int nb_c = (int)(((long long)E + CH - 1) / CH);

    // ---- prep + binning + fused CSR build (4 dispatches) ----
    k_prep<<<128, 256, 0, stream>>>(W1, W2, wt1, wt2, bcnt, dcnt, NBKT);
    k_bincount_scan<<<256, 256, 0, stream>>>(dst, bcnt, bofs, bcur, dcnt, E, NBKT, 256);
    k_binfill<<<nb_c, 256, 0, stream>>>(src, dst, bcur, recs, E, NBKT);
    k_fill_all<<<NBKT, 256, 0, stream>>>(recs, bofs, dinv, ofs, col, N, E);

    // ---- layer 1: ts = dinv*(x@W1); h16 = relu(b1 + dinv*(ts[d] + sum ts[col])) ----
    k_gemm_mfma<0><<<nb_g, 256, 0, stream>>>(x, wt1, dinv, t, N);
    k_agg_csr<1><<<nb_a, 256, 0, stream>>>(ofs, col, dinv, (const half4v*)t, b1, h16, N);

    // ---- layer 2: ts = dinv*(h16@W2); out = b2 + dinv*(ts[d] + sum ts[col]) ----
    k_gemm_mfma<1><<<nb_g, 256, 0, stream>>>(h16, wt2, dinv, t, N);
    k_agg_csr<0><<<nb_a, 256, 0, stream>>>(ofs, col, dinv, (const half4v*)t, b2, out, N);
}